// Round 1
// baseline (250.924 us; speedup 1.0000x reference)
//
#include <hip/hip_runtime.h>
#include <hip/hip_bf16.h>

// Problem dims (fixed by reference)
#define B_ROWS   8192
#define K_DIM    2048
#define OUT_COLS 4096
#define GROUP    128      // OUT_COLS / 32 groups
#define EPS      1e-5f

// GEMM tile
#define BM 128
#define BN 128
#define BK 64

using f32x4  = __attribute__((ext_vector_type(4))) float;
using bf16x8 = __attribute__((ext_vector_type(8))) short;   // 8 bf16 in 4 VGPRs

__device__ __forceinline__ unsigned short f2bf_rn(float f) {
    unsigned u = __builtin_bit_cast(unsigned, f);
    u += 0x7FFFu + ((u >> 16) & 1u);   // round-to-nearest-even (inputs are finite)
    return (unsigned short)(u >> 16);
}

__global__ void cvt_bf16(const float* __restrict__ in, unsigned short* __restrict__ out, int n4) {
    int stride = gridDim.x * blockDim.x;
    for (int i = blockIdx.x * blockDim.x + threadIdx.x; i < n4; i += stride) {
        float4 v = reinterpret_cast<const float4*>(in)[i];
        ushort4 r;
        r.x = f2bf_rn(v.x); r.y = f2bf_rn(v.y); r.z = f2bf_rn(v.z); r.w = f2bf_rn(v.w);
        reinterpret_cast<ushort4*>(out)[i] = r;
    }
}

__device__ __forceinline__ void gload_lds16(const unsigned short* src, unsigned short* lds) {
    __builtin_amdgcn_global_load_lds((const __attribute__((address_space(1))) void*)src,
                                     (__attribute__((address_space(3))) void*)lds,
                                     16, 0, 0);
}

// Fused bf16 GEMM (y = A @ W^T + bias) + GroupNorm(128 cols/group) + hardtanh.
// Block tile 128x128 => exactly one group in N, so groupnorm is block-local.
// 4 waves arranged 2(M) x 2(N); each wave 64x64 via 4x4 frags of mfma 16x16x32.
__global__ __launch_bounds__(256) void gemm_gn(const unsigned short* __restrict__ A,  // [8192][2048] bf16
                                               const unsigned short* __restrict__ Bw, // [4096][2048] bf16
                                               const float* __restrict__ bias,        // [4096]
                                               float* __restrict__ out) {             // [8192][4096] f32
    __shared__ __align__(16) unsigned short As[BM * BK];   // [128][64]
    __shared__ __align__(16) unsigned short Bs[BN * BK];   // [128][64]
    __shared__ float red[BM][2][2];                        // [row][wc][{sum,sumsq}]

    const int t    = threadIdx.x;
    const int lane = t & 63;
    const int wave = t >> 6;
    const int wr   = wave >> 1;       // 0..1  (M direction)
    const int wc   = wave & 1;        // 0..1  (N direction)
    const int l16  = lane & 15;
    const int lhi  = lane >> 4;

    // XCD-aware bijective swizzle: grid = 2048 = 64(brow) x 32(bcol), 2048 % 8 == 0
    const int bid = blockIdx.x;
    const int cpx = gridDim.x >> 3;
    const int swz = (bid & 7) * cpx + (bid >> 3);
    const int brow = swz >> 5;        // 0..63
    const int bcol = swz & 31;        // 0..31

    f32x4 acc[4][4] = {};

    const unsigned short* Abase = A  + (size_t)(brow * BM) * K_DIM;
    const unsigned short* Bbase = Bw + (size_t)(bcol * BN) * K_DIM;

    for (int kt = 0; kt < K_DIM / BK; ++kt) {
        // ---- stage A,B tiles: 8 x global_load_lds_dwordx4 (16B/lane) ----
        #pragma unroll
        for (int i = 0; i < 4; ++i) {
            int off = i * 2048 + t * 8;          // flat bf16 elem offset in tile
            int r = off >> 6;                    // row 0..127
            int k = off & 63;                    // col 0..63
            gload_lds16(Abase + (size_t)r * K_DIM + kt * BK + k, &As[off]);
            gload_lds16(Bbase + (size_t)r * K_DIM + kt * BK + k, &Bs[off]);
        }
        __syncthreads();   // drains vmcnt: tiles resident

        // ---- frags + MFMA ----
        bf16x8 a[4][2], b[4][2];
        #pragma unroll
        for (int m = 0; m < 4; ++m) {
            #pragma unroll
            for (int kk = 0; kk < 2; ++kk) {
                a[m][kk] = *reinterpret_cast<const bf16x8*>(&As[(wr * 64 + m * 16 + l16) * BK + kk * 32 + lhi * 8]);
                b[m][kk] = *reinterpret_cast<const bf16x8*>(&Bs[(wc * 64 + m * 16 + l16) * BK + kk * 32 + lhi * 8]);
            }
        }
        #pragma unroll
        for (int kk = 0; kk < 2; ++kk)
            #pragma unroll
            for (int m = 0; m < 4; ++m)
                #pragma unroll
                for (int n = 0; n < 4; ++n)
                    acc[m][n] = __builtin_amdgcn_mfma_f32_16x16x32_bf16(a[m][kk], b[n][kk], acc[m][n], 0, 0, 0);
        __syncthreads();   // LDS reusable next iter
    }

    // ---- epilogue: bias + groupnorm(128 cols = this block's N extent) + clip ----
    float bv[4];
    #pragma unroll
    for (int n = 0; n < 4; ++n)
        bv[n] = bias[bcol * BN + wc * 64 + n * 16 + l16];

    // C/D layout (16x16): col = lane&15, row = (lane>>4)*4 + j
    #pragma unroll
    for (int m = 0; m < 4; ++m) {
        #pragma unroll
        for (int j = 0; j < 4; ++j) {
            float s = 0.f, s2 = 0.f;
            #pragma unroll
            for (int n = 0; n < 4; ++n) {
                float v = acc[m][n][j] + bv[n];
                acc[m][n][j] = v;
                s += v; s2 += v * v;
            }
            // reduce across the 16 lanes holding this row (xor masks stay in-group)
            #pragma unroll
            for (int o = 1; o < 16; o <<= 1) {
                s  += __shfl_xor(s,  o);
                s2 += __shfl_xor(s2, o);
            }
            if (l16 == 0) {
                int r = wr * 64 + m * 16 + lhi * 4 + j;
                red[r][wc][0] = s;
                red[r][wc][1] = s2;
            }
        }
    }
    __syncthreads();

    #pragma unroll
    for (int m = 0; m < 4; ++m) {
        #pragma unroll
        for (int j = 0; j < 4; ++j) {
            const int rl   = wr * 64 + m * 16 + lhi * 4 + j;
            const float s  = red[rl][0][0] + red[rl][1][0];
            const float s2 = red[rl][0][1] + red[rl][1][1];
            const float mean = s * (1.0f / 128.0f);
            const float var  = s2 * (1.0f / 128.0f) - mean * mean;
            const float rstd = rsqrtf(var + EPS);
            float* orow = out + (size_t)(brow * BM + rl) * OUT_COLS + bcol * BN + wc * 64 + l16;
            #pragma unroll
            for (int n = 0; n < 4; ++n) {
                float v = (acc[m][n][j] - mean) * rstd;
                v = fminf(fmaxf(v, -1.0f), 1.0f);
                orow[n * 16] = v;
            }
        }
    }
}

extern "C" void kernel_launch(void* const* d_in, const int* in_sizes, int n_in,
                              void* d_out, int out_size, void* d_ws, size_t ws_size,
                              hipStream_t stream) {
    const float* x    = (const float*)d_in[0];   // [8192][2048]
    const float* w    = (const float*)d_in[1];   // [4096][2048]
    const float* bias = (const float*)d_in[2];   // [4096]
    float* out        = (float*)d_out;           // [8192][4096]

    // workspace: bf16 copies of x (32MB) and W (16MB); requires ws_size >= ~50.4MB
    unsigned short* xb = (unsigned short*)d_ws;
    unsigned short* wb = xb + (size_t)B_ROWS * K_DIM;

    cvt_bf16<<<2048, 256, 0, stream>>>(x, xb, (B_ROWS * K_DIM) / 4);
    cvt_bf16<<<1024, 256, 0, stream>>>(w, wb, (OUT_COLS * K_DIM) / 4);

    dim3 grid((B_ROWS / BM) * (OUT_COLS / BN));   // 64 * 32 = 2048
    gemm_gn<<<grid, 256, 0, stream>>>(xb, wb, bias, out);
}

// Round 2
// 173.349 us; speedup vs baseline: 1.4475x; 1.4475x over previous
//
#include <hip/hip_runtime.h>
#include <hip/hip_bf16.h>

// Problem dims (fixed by reference)
#define B_ROWS   8192
#define K_DIM    2048
#define OUT_COLS 4096
#define EPS      1e-5f

// GEMM tile (m201 8-phase template geometry)
#define BM 256
#define BN 256
#define BK 64
#define NT (K_DIM / BK)   // 32 K-tiles

using f32x4  = __attribute__((ext_vector_type(4))) float;
using bf16x8 = __attribute__((ext_vector_type(8))) short;   // 8 bf16 = 4 VGPRs

__device__ __forceinline__ unsigned short f2bf_rn(float f) {
    unsigned u = __builtin_bit_cast(unsigned, f);
    u += 0x7FFFu + ((u >> 16) & 1u);   // RNE (inputs finite)
    return (unsigned short)(u >> 16);
}

__global__ void cvt_bf16(const float* __restrict__ in, unsigned short* __restrict__ out, int n4) {
    int stride = gridDim.x * blockDim.x;
    for (int i = blockIdx.x * blockDim.x + threadIdx.x; i < n4; i += stride) {
        float4 v = reinterpret_cast<const float4*>(in)[i];
        ushort4 r;
        r.x = f2bf_rn(v.x); r.y = f2bf_rn(v.y); r.z = f2bf_rn(v.z); r.w = f2bf_rn(v.w);
        reinterpret_cast<ushort4*>(out)[i] = r;
    }
}

__device__ __forceinline__ void gload16(const unsigned short* src, unsigned short* lds) {
    __builtin_amdgcn_global_load_lds((const __attribute__((address_space(1))) void*)src,
                                     (__attribute__((address_space(3))) void*)lds,
                                     16, 0, 0);
}

// --- stage one half-tile (128 rows x 64 cols, 2 gload_lds/thread), dest linear,
//     source pre-swizzled so a swizzled READ (byte ^= (row&7)<<4) sees linear data.
#define STA(BUF, H, KT) do {                                                        \
    gload16(Ag + (H)*262144 + (KT)*64 + goff0, &As[BUF][(H)*8192 + lds0]);          \
    gload16(Ag + (H)*262144 + (KT)*64 + goff1, &As[BUF][(H)*8192 + lds1]);          \
  } while (0)
#define STB(BUF, H, KT) do {                                                        \
    gload16(Bg + (H)*262144 + (KT)*64 + goff0, &Bs[BUF][(H)*8192 + lds0]);          \
    gload16(Bg + (H)*262144 + (KT)*64 + goff1, &Bs[BUF][(H)*8192 + lds1]);          \
  } while (0)

#define LDB(BUF) do {                                                               \
    _Pragma("unroll") for (int n = 0; n < 4; ++n) {                                 \
      const int ro = browb + n * 16 * BK;                                           \
      bb[n][0] = *(const bf16x8*)&Bs[BUF][ro + colsw0];                             \
      bb[n][1] = *(const bf16x8*)&Bs[BUF][ro + colsw1];                             \
    } } while (0)

#define VW4 asm volatile("s_waitcnt vmcnt(4)" ::: "memory")

// One phase: ds_read A-quadrant -> stage issue -> barrier -> lgkmcnt(0) ->
// setprio(1) 16xMFMA setprio(0) -> [q3: vmcnt(4)] -> barrier.
#define DO_PHASE(Q, CURA, STAGE, TAILW) do {                                        \
    bf16x8 af[2][2];                                                                \
    _Pragma("unroll") for (int dm = 0; dm < 2; ++dm) {                              \
      const int ro = arow + (2*(Q)+dm) * 16 * BK;                                   \
      af[dm][0] = *(const bf16x8*)&(CURA)[ro + colsw0];                             \
      af[dm][1] = *(const bf16x8*)&(CURA)[ro + colsw1];                             \
    }                                                                               \
    STAGE;                                                                          \
    __builtin_amdgcn_s_barrier();                                                   \
    asm volatile("s_waitcnt lgkmcnt(0)" ::: "memory");                              \
    __builtin_amdgcn_sched_barrier(0);                                              \
    __builtin_amdgcn_s_setprio(1);                                                  \
    _Pragma("unroll") for (int kk = 0; kk < 2; ++kk)                                \
      _Pragma("unroll") for (int dm = 0; dm < 2; ++dm)                              \
        _Pragma("unroll") for (int n = 0; n < 4; ++n)                               \
          acc[2*(Q)+dm][n] = __builtin_amdgcn_mfma_f32_16x16x32_bf16(               \
              af[dm][kk], bb[n][kk], acc[2*(Q)+dm][n], 0, 0, 0);                    \
    __builtin_amdgcn_s_setprio(0);                                                  \
    TAILW;                                                                          \
    __builtin_amdgcn_s_barrier();                                                   \
    asm volatile("" ::: "memory");                                                  \
  } while (0)

__global__ __launch_bounds__(512, 2) void gemm_gn(const unsigned short* __restrict__ A,
                                                  const unsigned short* __restrict__ Bw,
                                                  const float* __restrict__ bias,
                                                  float* __restrict__ out) {
    __shared__ __align__(16) unsigned short As[2][BM * BK];   // 2 x 32 KB
    __shared__ __align__(16) unsigned short Bs[2][BN * BK];   // 2 x 32 KB

    const int tid  = threadIdx.x;
    const int lane = tid & 63;
    const int wave = tid >> 6;        // 0..7
    const int wr   = wave >> 2;       // 0..1 (M)
    const int wcn  = wave & 3;        // 0..3 (N)
    const int l16  = lane & 15;
    const int lhi  = lane >> 4;

    // T1: XCD-aware bijective swizzle (512 % 8 == 0)
    const int bid  = blockIdx.x;
    const int swz  = (bid & 7) * (gridDim.x >> 3) + (bid >> 3);
    const int brow = swz >> 4;        // 0..31
    const int bcol = swz & 15;        // 0..15

    // staging per-thread offsets (inverse-swizzled global source, linear LDS dest)
    int goff0, goff1, lds0, lds1;
    {
        int f0 = tid;          int r0 = f0 >> 3;
        int f1 = 512 + tid;    int r1 = f1 >> 3;
        goff0 = r0 * K_DIM + (((f0 & 7) ^ (r0 & 7)) * 8);
        goff1 = r1 * K_DIM + (((f1 & 7) ^ (r1 & 7)) * 8);
        lds0  = f0 * 8;
        lds1  = f1 * 8;
    }
    const unsigned short* Ag = A  + (size_t)brow * BM * K_DIM;
    const unsigned short* Bg = Bw + (size_t)bcol * BN * K_DIM;

    // swizzled fragment-read column offsets (ushort units); row&7 == l16&7
    const int colsw0 = (0 * 32 + lhi * 8) ^ ((l16 & 7) << 3);
    const int colsw1 = (1 * 32 + lhi * 8) ^ ((l16 & 7) << 3);
    const int arow   = (wr * 128 + l16) * BK;
    const int browb  = (wcn * 64 + l16) * BK;

    f32x4 acc[8][4] = {};

    // ---- prologue: A(0)h0,h1  B(0)h0,h1  B(1)h0,h1 ; keep B(1)'s 4 loads in flight
    STA(0, 0, 0); STA(0, 1, 0);
    STB(0, 0, 0); STB(0, 1, 0);
    STB(1, 0, 1); STB(1, 1, 1);
    asm volatile("s_waitcnt vmcnt(4)" ::: "memory");
    __builtin_amdgcn_s_barrier();
    asm volatile("" ::: "memory");

    const unsigned short* A0p = &As[0][0];
    const unsigned short* A1p = &As[1][0];

    #pragma unroll 1
    for (int tt = 0; tt < NT; tt += 2) {
        const int k1 = (tt + 1) & (NT - 1);
        const int k2 = (tt + 2) & (NT - 1);
        const int k3 = (tt + 3) & (NT - 1);
        bf16x8 bb[4][2];
        // ---- tile tt (buf0) ----
        LDB(0);
        DO_PHASE(0, A0p, STA(1, 0, k1),                 (void)0);
        DO_PHASE(1, A0p, STA(1, 1, k1); STB(0, 0, k2),  (void)0);
        DO_PHASE(2, A0p, STB(0, 1, k2),                 (void)0);
        DO_PHASE(3, A0p, (void)0,                       VW4);
        // ---- tile tt+1 (buf1) ----
        LDB(1);
        DO_PHASE(0, A1p, STA(0, 0, k2),                 (void)0);
        DO_PHASE(1, A1p, STA(0, 1, k2); STB(1, 0, k3),  (void)0);
        DO_PHASE(2, A1p, STB(1, 1, k3),                 (void)0);
        DO_PHASE(3, A1p, (void)0,                       VW4);
    }

    // ---- epilogue: drain dummy stages, reuse LDS for GroupNorm reduction ----
    asm volatile("s_waitcnt vmcnt(0)" ::: "memory");
    __syncthreads();
    float* red = (float*)&As[0][0];   // [256 rows][4 wcn][2] = 8 KB

    float bv[4];
    #pragma unroll
    for (int n = 0; n < 4; ++n)
        bv[n] = bias[bcol * BN + wcn * 64 + n * 16 + l16];

    // pass 1: add bias, per-row partial sums over this wave's 64 cols,
    // 16-lane shuffle reduce (C/D layout: col = lane&15, row = (lane>>4)*4 + j)
    #pragma unroll
    for (int m = 0; m < 8; ++m) {
        #pragma unroll
        for (int j = 0; j < 4; ++j) {
            float s = 0.f, s2 = 0.f;
            #pragma unroll
            for (int n = 0; n < 4; ++n) {
                float v = acc[m][n][j] + bv[n];
                acc[m][n][j] = v;
                s += v; s2 += v * v;
            }
            #pragma unroll
            for (int o = 1; o < 16; o <<= 1) {
                s  += __shfl_xor(s,  o);
                s2 += __shfl_xor(s2, o);
            }
            if (l16 == 0) {
                int r = wr * 128 + m * 16 + lhi * 4 + j;
                red[r * 8 + wcn * 2 + 0] = s;
                red[r * 8 + wcn * 2 + 1] = s2;
            }
        }
    }
    __syncthreads();

    // pass 2: combine the two waves covering each 128-col group, normalize, clip, store
    const int p2 = (wcn & 2) * 2;   // base index of this group's wave pair
    #pragma unroll
    for (int m = 0; m < 8; ++m) {
        #pragma unroll
        for (int j = 0; j < 4; ++j) {
            const int r   = wr * 128 + m * 16 + lhi * 4 + j;
            const float s  = red[r * 8 + p2 + 0] + red[r * 8 + p2 + 2];
            const float s2 = red[r * 8 + p2 + 1] + red[r * 8 + p2 + 3];
            const float mean = s * (1.0f / 128.0f);
            const float var  = s2 * (1.0f / 128.0f) - mean * mean;
            const float rstd = rsqrtf(var + EPS);
            float* orow = out + (size_t)(brow * BM + r) * OUT_COLS + bcol * BN + wcn * 64 + l16;
            #pragma unroll
            for (int n = 0; n < 4; ++n) {
                float v = (acc[m][n][j] - mean) * rstd;
                v = fminf(fmaxf(v, -1.0f), 1.0f);
                orow[n * 16] = v;
            }
        }
    }
}

extern "C" void kernel_launch(void* const* d_in, const int* in_sizes, int n_in,
                              void* d_out, int out_size, void* d_ws, size_t ws_size,
                              hipStream_t stream) {
    const float* x    = (const float*)d_in[0];   // [8192][2048]
    const float* w    = (const float*)d_in[1];   // [4096][2048]
    const float* bias = (const float*)d_in[2];   // [4096]
    float* out        = (float*)d_out;           // [8192][4096]

    unsigned short* xb = (unsigned short*)d_ws;
    unsigned short* wb = xb + (size_t)B_ROWS * K_DIM;

    cvt_bf16<<<2048, 256, 0, stream>>>(x, xb, (B_ROWS * K_DIM) / 4);
    cvt_bf16<<<1024, 256, 0, stream>>>(w, wb, (OUT_COLS * K_DIM) / 4);

    dim3 grid((B_ROWS / BM) * (OUT_COLS / BN));   // 32 * 16 = 512
    gemm_gn<<<grid, 512, 0, stream>>>(xb, wb, bias, out);
}

// Round 3
// 168.664 us; speedup vs baseline: 1.4877x; 1.0278x over previous
//
#include <hip/hip_runtime.h>
#include <hip/hip_bf16.h>

// Problem dims (fixed by reference)
#define B_ROWS   8192
#define K_DIM    2048
#define OUT_COLS 4096
#define EPS      1e-5f

// GEMM tile (256^2 8-phase template, fragment reads pipelined 1 phase ahead)
#define BM 256
#define BN 256
#define BK 64
#define NT (K_DIM / BK)   // 32 K-tiles

using f32x4  = __attribute__((ext_vector_type(4))) float;
using bf16x8 = __attribute__((ext_vector_type(8))) short;   // 8 bf16 = 4 VGPRs

__device__ __forceinline__ unsigned short f2bf_rn(float f) {
    unsigned u = __builtin_bit_cast(unsigned, f);
    u += 0x7FFFu + ((u >> 16) & 1u);   // RNE (inputs finite)
    return (unsigned short)(u >> 16);
}

__global__ void cvt_bf16(const float* __restrict__ in, unsigned short* __restrict__ out, int n4) {
    int stride = gridDim.x * blockDim.x;
    for (int i = blockIdx.x * blockDim.x + threadIdx.x; i < n4; i += stride) {
        float4 v = reinterpret_cast<const float4*>(in)[i];
        ushort4 r;
        r.x = f2bf_rn(v.x); r.y = f2bf_rn(v.y); r.z = f2bf_rn(v.z); r.w = f2bf_rn(v.w);
        reinterpret_cast<ushort4*>(out)[i] = r;
    }
}

__device__ __forceinline__ void gload16(const unsigned short* src, unsigned short* lds) {
    __builtin_amdgcn_global_load_lds((const __attribute__((address_space(1))) void*)src,
                                     (__attribute__((address_space(3))) void*)lds,
                                     16, 0, 0);
}

// stage one half-tile (128 rows x 64 cols): linear LDS dest, inverse-swizzled global src
#define STA(BUF, H, KT) do {                                                        \
    gload16(Ag + (H)*262144 + (KT)*64 + goff0, &As[BUF][(H)*8192 + lds0]);          \
    gload16(Ag + (H)*262144 + (KT)*64 + goff1, &As[BUF][(H)*8192 + lds1]);          \
  } while (0)
#define STB(BUF, H, KT) do {                                                        \
    gload16(Bg + (H)*262144 + (KT)*64 + goff0, &Bs[BUF][(H)*8192 + lds0]);          \
    gload16(Bg + (H)*262144 + (KT)*64 + goff1, &Bs[BUF][(H)*8192 + lds1]);          \
  } while (0)

// read the 8 B-fragments of a tile (consumed starting NEXT phase)
#define RD_B(CURB) do {                                                             \
    _Pragma("unroll") for (int n = 0; n < 4; ++n) {                                 \
      const int ro = browb + n * 16 * BK;                                           \
      bb[n][0] = *(const bf16x8*)&(CURB)[ro + colsw0];                              \
      bb[n][1] = *(const bf16x8*)&(CURB)[ro + colsw1];                              \
    } } while (0)

// read one A-quadrant (2 m-frags x 2 k) into ping-pong slot (consumed NEXT phase)
#define RD_A(SLOT, CURA, Q) do {                                                    \
    _Pragma("unroll") for (int dm = 0; dm < 2; ++dm) {                              \
      const int ro = arow + (2*(Q)+dm) * 16 * BK;                                   \
      af[SLOT][dm][0] = *(const bf16x8*)&(CURA)[ro + colsw0];                       \
      af[SLOT][dm][1] = *(const bf16x8*)&(CURA)[ro + colsw1];                       \
    } } while (0)

#define MFMA16(SLOT, Q) do {                                                        \
    __builtin_amdgcn_s_setprio(1);                                                  \
    _Pragma("unroll") for (int kk = 0; kk < 2; ++kk)                                \
      _Pragma("unroll") for (int dm = 0; dm < 2; ++dm)                              \
        _Pragma("unroll") for (int n = 0; n < 4; ++n)                               \
          acc[2*(Q)+dm][n] = __builtin_amdgcn_mfma_f32_16x16x32_bf16(               \
              af[SLOT][dm][kk], bb[n][kk], acc[2*(Q)+dm][n], 0, 0, 0);              \
    __builtin_amdgcn_s_setprio(0);                                                  \
  } while (0)

#define VW4  asm volatile("s_waitcnt vmcnt(4)" ::: "memory")
#define BAR  __builtin_amdgcn_s_barrier()

__global__ __launch_bounds__(512, 2) void gemm_gn(const unsigned short* __restrict__ A,
                                                  const unsigned short* __restrict__ Bw,
                                                  const float* __restrict__ bias,
                                                  float* __restrict__ out) {
    __shared__ __align__(16) unsigned short As[2][BM * BK];   // 2 x 32 KB
    __shared__ __align__(16) unsigned short Bs[2][BN * BK];   // 2 x 32 KB

    const int tid  = threadIdx.x;
    const int lane = tid & 63;
    const int wave = tid >> 6;        // 0..7
    const int wr   = wave >> 2;       // 0..1 (M)
    const int wcn  = wave & 3;        // 0..3 (N)
    const int l16  = lane & 15;
    const int lhi  = lane >> 4;

    // T1: XCD-aware bijective swizzle (512 % 8 == 0)
    const int bid  = blockIdx.x;
    const int swz  = (bid & 7) * (gridDim.x >> 3) + (bid >> 3);
    const int brow = swz >> 4;        // 0..31
    const int bcol = swz & 15;        // 0..15

    // staging per-thread offsets (inverse-swizzled global source, linear LDS dest)
    int goff0, goff1, lds0, lds1;
    {
        int f0 = tid;          int r0 = f0 >> 3;
        int f1 = 512 + tid;    int r1 = f1 >> 3;
        goff0 = r0 * K_DIM + (((f0 & 7) ^ (r0 & 7)) * 8);
        goff1 = r1 * K_DIM + (((f1 & 7) ^ (r1 & 7)) * 8);
        lds0  = f0 * 8;
        lds1  = f1 * 8;
    }
    const unsigned short* Ag = A  + (size_t)brow * BM * K_DIM;
    const unsigned short* Bg = Bw + (size_t)bcol * BN * K_DIM;

    // swizzled fragment-read column offsets (ushort units); row&7 == l16&7
    const int colsw0 = (0 * 32 + lhi * 8) ^ ((l16 & 7) << 3);
    const int colsw1 = (1 * 32 + lhi * 8) ^ ((l16 & 7) << 3);
    const int arow   = (wr * 128 + l16) * BK;
    const int browb  = (wcn * 64 + l16) * BK;

    const unsigned short* A0p = &As[0][0];
    const unsigned short* A1p = &As[1][0];
    const unsigned short* B0p = &Bs[0][0];
    const unsigned short* B1p = &Bs[1][0];

    f32x4  acc[8][4] = {};
    bf16x8 af[2][2][2];
    bf16x8 bb[4][2];

    // ---- prologue: A(0)->As0, B(0)->Bs0, B(1)->Bs1; leave B(1)'s 4 in flight
    STA(0, 0, 0); STA(0, 1, 0);
    STB(0, 0, 0); STB(0, 1, 0);
    STB(1, 0, 1); STB(1, 1, 1);
    VW4;                       // A(0), B(0) landed
    BAR;
    RD_A(0, A0p, 0);           // in flight for ph0
    RD_B(B0p);

    #pragma unroll 1
    for (int tt = 0; tt < NT; tt += 2) {
        const int k1 = (tt + 1) & (NT - 1);
        const int k2 = (tt + 2) & (NT - 1);
        const int k3 = (tt + 3) & (NT - 1);
        // ---- tile tt (buf0) ----
        RD_A(1, A0p, 1); STA(1, 0, k1);               MFMA16(0, 0);       BAR;
        RD_A(0, A0p, 2); STA(1, 1, k1); STB(0, 0, k2); MFMA16(1, 1);      BAR;
        RD_A(1, A0p, 3); STB(0, 1, k2);               MFMA16(0, 2); VW4;  BAR;
        RD_A(0, A1p, 0);                              MFMA16(1, 3); RD_B(B1p); BAR;
        // ---- tile tt+1 (buf1) ----
        RD_A(1, A1p, 1); STA(0, 0, k2);               MFMA16(0, 0);       BAR;
        RD_A(0, A1p, 2); STA(0, 1, k2); STB(1, 0, k3); MFMA16(1, 1);      BAR;
        RD_A(1, A1p, 3); STB(1, 1, k3);               MFMA16(0, 2); VW4;  BAR;
        RD_A(0, A0p, 0);                              MFMA16(1, 3); RD_B(B0p); BAR;
    }

    // ---- epilogue: drain dummy stages, reuse LDS for GroupNorm reduction ----
    asm volatile("s_waitcnt vmcnt(0)" ::: "memory");
    __syncthreads();
    float* red = (float*)&As[0][0];   // [256 rows][4 wcn][2] = 8 KB

    float bv[4];
    #pragma unroll
    for (int n = 0; n < 4; ++n)
        bv[n] = bias[bcol * BN + wcn * 64 + n * 16 + l16];

    // pass 1: add bias, per-row partial sums over this wave's 64 cols,
    // 16-lane shuffle reduce (C/D layout: col = lane&15, row = (lane>>4)*4 + j)
    #pragma unroll
    for (int m = 0; m < 8; ++m) {
        #pragma unroll
        for (int j = 0; j < 4; ++j) {
            float s = 0.f, s2 = 0.f;
            #pragma unroll
            for (int n = 0; n < 4; ++n) {
                float v = acc[m][n][j] + bv[n];
                acc[m][n][j] = v;
                s += v; s2 += v * v;
            }
            #pragma unroll
            for (int o = 1; o < 16; o <<= 1) {
                s  += __shfl_xor(s,  o);
                s2 += __shfl_xor(s2, o);
            }
            if (l16 == 0) {
                int r = wr * 128 + m * 16 + lhi * 4 + j;
                red[r * 8 + wcn * 2 + 0] = s;
                red[r * 8 + wcn * 2 + 1] = s2;
            }
        }
    }
    __syncthreads();

    // pass 2: combine the two waves covering each 128-col group, normalize, clip, store
    const int p2 = (wcn & 2) * 2;   // base index of this group's wave pair
    #pragma unroll
    for (int m = 0; m < 8; ++m) {
        #pragma unroll
        for (int j = 0; j < 4; ++j) {
            const int r   = wr * 128 + m * 16 + lhi * 4 + j;
            const float s  = red[r * 8 + p2 + 0] + red[r * 8 + p2 + 2];
            const float s2 = red[r * 8 + p2 + 1] + red[r * 8 + p2 + 3];
            const float mean = s * (1.0f / 128.0f);
            const float var  = s2 * (1.0f / 128.0f) - mean * mean;
            const float rstd = rsqrtf(var + EPS);
            float* orow = out + (size_t)(brow * BM + r) * OUT_COLS + bcol * BN + wcn * 64 + l16;
            #pragma unroll
            for (int n = 0; n < 4; ++n) {
                float v = (acc[m][n][j] - mean) * rstd;
                v = fminf(fmaxf(v, -1.0f), 1.0f);
                orow[n * 16] = v;
            }
        }
    }
}

extern "C" void kernel_launch(void* const* d_in, const int* in_sizes, int n_in,
                              void* d_out, int out_size, void* d_ws, size_t ws_size,
                              hipStream_t stream) {
    const float* x    = (const float*)d_in[0];   // [8192][2048]
    const float* w    = (const float*)d_in[1];   // [4096][2048]
    const float* bias = (const float*)d_in[2];   // [4096]
    float* out        = (float*)d_out;           // [8192][4096]

    unsigned short* xb = (unsigned short*)d_ws;
    unsigned short* wb = xb + (size_t)B_ROWS * K_DIM;

    cvt_bf16<<<2048, 256, 0, stream>>>(x, xb, (B_ROWS * K_DIM) / 4);
    cvt_bf16<<<1024, 256, 0, stream>>>(w, wb, (OUT_COLS * K_DIM) / 4);

    dim3 grid((B_ROWS / BM) * (OUT_COLS / BN));   // 32 * 16 = 512
    gemm_gn<<<grid, 512, 0, stream>>>(xb, wb, bias, out);
}